// Round 12
// baseline (176.133 us; speedup 1.0000x reference)
//
#include <hip/hip_runtime.h>

#define B_    32
#define CIN   256
#define COUT  256
#define Hh    56
#define Ww    56
#define HP    58
#define WP    58
#define Kk    2304   // 9 taps * 256 ci
#define NT    36     // K-tiles of BK=64

#define QSCALE 2016.0f
#define QINV   (1.0f/2016.0f)

#define XPAD_BYTES ((size_t)B_*HP*WP*CIN)     // 27,557,888 i8
#define XPAD_GUARD 4096                        // wp-overrun guard (reads only)
#define AWT_OFF    (XPAD_BYTES + XPAD_GUARD)
#define AWT_BYTES  ((size_t)NT*16384)          // weights tiled [kt][kc][co][16]
#define WS_REQUIRED (AWT_OFF + AWT_BYTES)

typedef __attribute__((ext_vector_type(4))) int i32x4;

__device__ __forceinline__ void gload_lds16(const void* g, void* l) {
  __builtin_amdgcn_global_load_lds(
      (const __attribute__((address_space(1))) unsigned int*)g,
      (__attribute__((address_space(3))) unsigned int*)l, 16, 0, 0);
}

// ---- prepass: gated weights -> i8, tiled [kt][kc(4)][co(256)][16]
// q = round(w * scale(mask) * 2016); grid=256 (co), block=256
__global__ __launch_bounds__(256) void prep_w8(const float* __restrict__ wgt,
                                               const float* __restrict__ mask,
                                               signed char* __restrict__ awt) {
  const int co = blockIdx.x, t = threadIdx.x;
  const float m = mask[co];
  const float sc = (m > 0.f ? 1.f : (m < 0.f ? 0.f : 0.5f)) * QSCALE;
  const float* wc = wgt + (size_t)co * Kk;       // [ci][tap]
  for (int o = t; o < Kk; o += 256) {
    int tap = o >> 8, ci = o & 255;
    int q = __float2int_rn(wc[ci * 9 + tap] * sc);
    int kt = tap * 4 + (ci >> 6);                // K-tile (64 k per tap-quarter)
    int kk = ci & 63;
    awt[((size_t)kt * 1024 + (kk >> 4) * 256 + co) * 16 + (kk & 15)] =
        (signed char)q;
  }
}

// ---- prepass: sign(x) -> i8 {-1,0,1}, zero-pad, NCHW -> [b][hp][wp][ci]
// grid=(HP, B_), block=256
__global__ __launch_bounds__(256) void prep_x8(const float* __restrict__ x,
                                               signed char* __restrict__ xp) {
  const int hp = blockIdx.x, b = blockIdx.y, t = threadIdx.x;
  unsigned* orow = (unsigned*)(xp + (size_t)(b * HP + hp) * WP * CIN);
  if (hp == 0 || hp == HP - 1) {
    for (int i = t; i < WP * CIN / 4; i += 256) orow[i] = 0u;
    return;
  }
  __shared__ __align__(16) signed char tile[WP * CIN];
  const int h = hp - 1;
  tile[t] = 0;                                   // wp=0 border (t covers ci)
  tile[(WP - 1) * CIN + t] = 0;                  // wp=57 border
  const int tx = t & 63, ty = t >> 6;
  if (tx < Ww) {
    const float* xr = x + ((size_t)b * CIN * Hh + h) * Ww;
    for (int ci = ty; ci < CIN; ci += 4) {
      float xv = xr[(size_t)ci * Hh * Ww + tx];
      tile[(1 + tx) * CIN + ci] = (xv > 0.f) ? 1 : (xv < 0.f ? -1 : 0);
    }
  }
  __syncthreads();
  for (int i = t; i < WP * CIN / 4; i += 256) orow[i] = ((const unsigned*)tile)[i];
}

// ---- main: i8 implicit GEMM, A-operand DIRECT FROM GLOBAL (L2-resident
// 590KB, fragment-ordered) into VGPRs, double-banked one KT ahead.
// B through LDS: per buffer [4 kc][256 n][16B] = 16KB, dbuf = 32KB total.
// 256x256 tile, BK=64, 8 waves of 128x64, mfma_i32_16x16x64_i8.
// Per KT: STAGE_B(kt+1) -> LOAD_A(kt+1) -> 4x ds_read_b128 -> 32 MFMA
// -> vmcnt(0) -> barrier.  LDS traffic 48KB/KT (was 128KB).
// grid=(448 = b*14 + hblk), block=512
__global__ __launch_bounds__(512, 2) void gemm_i8r(
    const signed char* __restrict__ xp,
    const signed char* __restrict__ awt,
    float* __restrict__ out) {
  extern __shared__ char smem[];

  const int t = threadIdx.x;
  const int nb = blockIdx.x;
  const int b = nb / 14, h0 = (nb % 14) * 4;

  const int wid = t >> 6, lane = t & 63;
  const int wm = wid >> 2, wn = wid & 3;         // wave tile: 128 M x 64 N
  const int lc = lane & 15, lr = lane >> 4;

  // A fragment source (global, fragment-ordered): + kt*16384 + i*256
  const signed char* awfrag = awt + lr * 4096 + (size_t)(wm * 128 + lc) * 16;
  // B fragment read base (LDS): + buf*16384 + i*256
  const int bbase = lr * 4096 + (wn * 64 + lc) * 16;

  // B staging: thread t covers lines {t, 512+t} (kc = line>>8, n = line&255)
  const int n = t & 255;
  const size_t xb = (size_t)b * HP;
  const signed char* xbp =
      xp + ((xb + h0 + (n >> 6)) * WP + (n & 63)) * CIN + (t >> 8) * 16;
  char* ldstB = smem + t * 16;

  i32x4 afA[8], afB[8], bf[4];
  i32x4 acc[8][4] = {};

#define STAGE_B(ktx, BUF) do {                                                 \
    int tap_ = (ktx) >> 2;                                                     \
    int kh_ = tap_ / 3, kw_ = tap_ - kh_ * 3;                                  \
    const signed char* s_ = xbp + (kh_ * WP + kw_) * CIN + ((ktx) & 3) * 64;   \
    char* d_ = ldstB + (BUF) * 16384;                                          \
    gload_lds16(s_, d_);                                                       \
    gload_lds16(s_ + 32, d_ + 8192);                                           \
  } while (0)

#define LOAD_A(ktx, AF) do { _Pragma("unroll")                                 \
    for (int i_ = 0; i_ < 8; ++i_)                                             \
      AF[i_] = *(const i32x4*)(awfrag + (size_t)(ktx) * 16384 + i_ * 256);     \
  } while (0)

#define READ_B(BUF) do { _Pragma("unroll")                                     \
    for (int i_ = 0; i_ < 4; ++i_)                                             \
      bf[i_] = *(const i32x4*)(smem + (BUF) * 16384 + bbase + i_ * 256);       \
  } while (0)

#define MFMA32(AF) do { _Pragma("unroll")                                      \
    for (int m_ = 0; m_ < 8; ++m_) { _Pragma("unroll")                         \
      for (int n_ = 0; n_ < 4; ++n_)                                           \
        acc[m_][n_] = __builtin_amdgcn_mfma_i32_16x16x64_i8(                   \
            AF[m_], bf[n_], acc[m_][n_], 0, 0, 0); }                           \
  } while (0)

#define ENDKT() do {                                                           \
    asm volatile("s_waitcnt vmcnt(0)" ::: "memory");                           \
    __builtin_amdgcn_sched_barrier(0);                                         \
    __builtin_amdgcn_s_barrier();                                              \
    __builtin_amdgcn_sched_barrier(0);                                         \
  } while (0)

  // prologue: A(kt0) -> afA, B(kt0) -> buf0
  LOAD_A(0, afA);
  STAGE_B(0, 0);
  ENDKT();

#pragma unroll 1
  for (int it = 0; it < NT / 2; ++it) {
    const int ka = 2 * it, kb = 2 * it + 1;
    const int ka1 = kb;                               // ka+1, always < NT
    const int kb1 = (kb + 1 < NT) ? kb + 1 : NT - 1;  // tail dummy ok
    // even KT: consume afA/buf0, prefetch afB/buf1
    STAGE_B(ka1, 1);
    LOAD_A(ka1, afB);
    READ_B(0);
    __builtin_amdgcn_s_setprio(1);
    MFMA32(afA);
    __builtin_amdgcn_s_setprio(0);
    ENDKT();
    // odd KT: consume afB/buf1, prefetch afA/buf0
    STAGE_B(kb1, 0);
    LOAD_A(kb1, afA);
    READ_B(1);
    __builtin_amdgcn_s_setprio(1);
    MFMA32(afB);
    __builtin_amdgcn_s_setprio(0);
    ENDKT();
  }

  // epilogue: C/D map col(n)=lane&15, row(m)=(lane>>4)*4+reg; scale back
  const int h = h0 + wn;
  #pragma unroll
  for (int m = 0; m < 8; ++m) {
    const int co = wm * 128 + m * 16 + lr * 4;
    #pragma unroll
    for (int nf = 0; nf < 4; ++nf) {
      const int w = nf * 16 + lc;
      if (w < Ww) {
        #pragma unroll
        for (int r = 0; r < 4; ++r)
          out[(((size_t)b * COUT + co + r) * Hh + h) * Ww + w] =
              (float)acc[m][nf][r] * QINV;
      }
    }
  }
}

// ---- fallback: proven-correct naive direct conv (used only if ws too small)
__global__ __launch_bounds__(256) void binconv_naive(
    const float* __restrict__ x,
    const float* __restrict__ wgt,
    const float* __restrict__ mask,
    float* __restrict__ out) {
  const int w  = threadIdx.x;
  const int h  = blockIdx.x * 4 + threadIdx.y;
  const int co = blockIdx.y;
  const int b  = blockIdx.z;

  const float m = mask[co];
  const float scale = (m > 0.f) ? 1.f : ((m < 0.f) ? 0.f : 0.5f);

  const size_t obase = (((size_t)b * COUT + co) * Hh + h) * Ww + w;
  if (scale == 0.f) {
    if (w < Ww) out[obase] = 0.f;
    return;
  }

  const float* __restrict__ xb = x   + (size_t)b  * CIN * Hh * Ww;
  const float* __restrict__ wc = wgt + (size_t)co * CIN * 9;

  float acc = 0.f;
  for (int ci = 0; ci < CIN; ++ci) {
    const float* __restrict__ xc = xb + (size_t)ci * (Hh * Ww);
    const float* __restrict__ wk = wc + ci * 9;
    float wv[9];
    #pragma unroll
    for (int t2 = 0; t2 < 9; ++t2) wv[t2] = wk[t2];
    #pragma unroll
    for (int kh = 0; kh < 3; ++kh) {
      const int hh = h + kh - 1;
      if (hh < 0 || hh >= Hh) continue;
      const float* __restrict__ xr = xc + hh * Ww;
      #pragma unroll
      for (int kw = 0; kw < 3; ++kw) {
        const int ww = w + kw - 1;
        float xv = (ww >= 0 && ww < Ww) ? xr[ww] : 0.f;
        float s = (xv > 0.f) ? 1.f : ((xv < 0.f) ? -1.f : 0.f);
        acc += s * wv[kh * 3 + kw];
      }
    }
  }
  if (w < Ww) out[obase] = acc * scale;
}

extern "C" void kernel_launch(void* const* d_in, const int* in_sizes, int n_in,
                              void* d_out, int out_size, void* d_ws, size_t ws_size,
                              hipStream_t stream) {
  const float* x    = (const float*)d_in[0];
  const float* wgt  = (const float*)d_in[1];
  const float* mask = (const float*)d_in[2];
  float* out = (float*)d_out;

  bool ok = ws_size >= WS_REQUIRED;
  if (ok) {
    hipError_t e = hipFuncSetAttribute(
        (const void*)gemm_i8r, hipFuncAttributeMaxDynamicSharedMemorySize,
        32768);
    ok = (e == hipSuccess);
  }
  if (!ok) {
    hipLaunchKernelGGL(binconv_naive, dim3(Hh / 4, COUT, B_), dim3(64, 4, 1),
                       0, stream, x, wgt, mask, out);
    return;
  }

  signed char* xp8 = (signed char*)d_ws;
  signed char* awt = (signed char*)d_ws + AWT_OFF;

  hipLaunchKernelGGL(prep_w8, dim3(COUT), dim3(256), 0, stream, wgt, mask, awt);
  hipLaunchKernelGGL(prep_x8, dim3(HP, B_), dim3(256), 0, stream, x, xp8);
  hipLaunchKernelGGL(gemm_i8r, dim3(448), dim3(512), 32768, stream,
                     xp8, awt, out);
}

// Round 14
// 125.025 us; speedup vs baseline: 1.4088x; 1.4088x over previous
//
#include <hip/hip_runtime.h>

#define B_    32
#define CIN   256
#define COUT  256
#define Hh    56
#define Ww    56
#define HP    58
#define WP    58
#define Kk    2304   // 9 taps * 256 ci
#define NT    36     // K-tiles of BK=64

#define QSCALE 2016.0f
#define QINV   (1.0f/2016.0f)

#define XPAD_BYTES ((size_t)B_*HP*WP*CIN)     // 27,557,888 i8
#define XPAD_GUARD 4096                        // wp-overrun guard (reads only)
#define AWT_OFF    (XPAD_BYTES + XPAD_GUARD)
#define AWT_BYTES  ((size_t)NT*16384)          // weights tiled [kt][kc][slot][16]
#define META_OFF   (AWT_OFF + AWT_BYTES)
#define WS_REQUIRED (META_OFF + 1040)

typedef __attribute__((ext_vector_type(4))) int i32x4;

__device__ __forceinline__ void gload_lds16(const void* g, void* l) {
  __builtin_amdgcn_global_load_lds(
      (const __attribute__((address_space(1))) unsigned int*)g,
      (__attribute__((address_space(3))) unsigned int*)l, 16, 0, 0);
}

// ---- prepass 0: mask -> perm[256] (active slots first) + act count
// meta[0] = act, meta[1..256] = perm. 1 block, 256 threads.
__global__ __launch_bounds__(256) void perm_k(const float* __restrict__ mask,
                                              int* __restrict__ meta) {
  __shared__ int sc[256];
  const int t = threadIdx.x;
  const int fl = (mask[t] >= 0.0f) ? 1 : 0;   // scale!=0 iff mask>=0
  sc[t] = fl;
  __syncthreads();
  for (int off = 1; off < 256; off <<= 1) {
    int v = sc[t];
    int u = (t >= off) ? sc[t - off] : 0;
    __syncthreads();
    sc[t] = v + u;
    __syncthreads();
  }
  const int incl = sc[t], act = sc[255];
  const int pos = fl ? (incl - 1) : (act + t - incl);
  meta[1 + pos] = t;
  if (t == 0) meta[0] = act;
}

// ---- prepass 1: gated weights -> i8, compacted-slot tiled [kt][kc][slot][16]
// block = slot; co = perm[slot]; inactive slots get scale 0 -> zero weights.
__global__ __launch_bounds__(256) void prep_w8(const float* __restrict__ wgt,
                                               const float* __restrict__ mask,
                                               const int* __restrict__ meta,
                                               signed char* __restrict__ awt) {
  const int slot = blockIdx.x, t = threadIdx.x;
  const int co = meta[1 + slot];
  const float m = mask[co];
  const float sc = (m > 0.f ? 1.f : (m < 0.f ? 0.f : 0.5f)) * QSCALE;
  const float* wc = wgt + (size_t)co * Kk;       // [ci][tap]
  for (int o = t; o < Kk; o += 256) {
    int tap = o >> 8, ci = o & 255;
    int q = __float2int_rn(wc[ci * 9 + tap] * sc);
    int kt = tap * 4 + (ci >> 6);
    int kk = ci & 63;
    awt[((size_t)kt * 1024 + (kk >> 4) * 256 + slot) * 16 + (kk & 15)] =
        (signed char)q;
  }
}

// ---- prepass 2: sign(x) -> i8 {-1,0,1}, zero-pad, NCHW -> [b][hp][wp][ci]
__global__ __launch_bounds__(256) void prep_x8(const float* __restrict__ x,
                                               signed char* __restrict__ xp) {
  const int hp = blockIdx.x, b = blockIdx.y, t = threadIdx.x;
  unsigned* orow = (unsigned*)(xp + (size_t)(b * HP + hp) * WP * CIN);
  if (hp == 0 || hp == HP - 1) {
    for (int i = t; i < WP * CIN / 4; i += 256) orow[i] = 0u;
    return;
  }
  __shared__ __align__(16) signed char tile[WP * CIN];
  const int h = hp - 1;
  tile[t] = 0;
  tile[(WP - 1) * CIN + t] = 0;
  const int tx = t & 63, ty = t >> 6;
  if (tx < Ww) {
    const float* xr = x + ((size_t)b * CIN * Hh + h) * Ww;
    for (int ci = ty; ci < CIN; ci += 4) {
      float xv = xr[(size_t)ci * Hh * Ww + tx];
      tile[(1 + tx) * CIN + ci] = (xv > 0.f) ? 1 : (xv < 0.f ? -1 : 0);
    }
  }
  __syncthreads();
  for (int i = t; i < WP * CIN / 4; i += 256) orow[i] = ((const unsigned*)tile)[i];
}

// ---- main: compacted-M i8 GEMM. BM=128 (grid_y=2 over slot-halves),
// BN=256 (4 padded rows), BK=64. 4 waves (2x2) of 64M x 128N, acc[4][8].
// LDS: tri-buffer x {A [4kc][128][16]=8KB @0, B [4kc][256][16]=16KB @8192}
// = 72KB; 2 blocks/CU. Depth-2 prefetch, counted vmcnt(6) per KT.
// ng = active 64-row groups of this block: ng==0 -> zero-exit;
// waves wm>=ng skip frag-reads+MFMA but stage uniformly (uniform vmcnt).
// grid=(448 = b*14 + hblk, 2), block=256
__global__ __launch_bounds__(256, 2) void gemm_i8c(
    const signed char* __restrict__ xp,
    const signed char* __restrict__ awt,
    const int* __restrict__ meta,
    float* __restrict__ out) {
  extern __shared__ char smem[];

  const int t = threadIdx.x;
  const int nb = blockIdx.x, by = blockIdx.y;
  const int b = nb / 14, h0 = (nb % 14) * 4;

  const int act = meta[0];
  const int rem = act - by * 128;
  const int ng = (rem <= 0) ? 0 : ((rem > 64) ? 2 : 1);

  const int wid = t >> 6, lane = t & 63;
  const int wm = wid >> 1, wn = wid & 1;     // wave tile: 64 M x 128 N
  const int lc = lane & 15, lr = lane >> 4;

  i32x4 acc[4][8] = {};

  if (ng > 0) {
    const signed char* awp =
        awt + (t >> 7) * 4096 + (size_t)(by * 128 + (t & 127)) * 16;
    const size_t xb = (size_t)b * HP;
    const signed char* xbp =
        xp + ((xb + h0 + (t >> 6)) * WP + (t & 63)) * CIN;
    char* dstA = smem + t * 16;
    char* dstB = smem + 8192 + t * 16;

    const int abase0 = lr * 2048 + (wm * 64 + lc) * 16;
    const int bbase0 = 8192 + lr * 4096 + (wn * 128 + lc) * 16;
    const bool run = (wm < ng);

#define STAGE_Ak(ktx, BO) do {                                                 \
    const signed char* s_ = awp + (size_t)(ktx) * 16384;                       \
    gload_lds16(s_, dstA + (BO));                                              \
    gload_lds16(s_ + 8192, dstA + (BO) + 4096);                                \
  } while (0)

#define STAGE_Bk(ktx, BO) do {                                                 \
    int tap_ = (ktx) >> 2;                                                     \
    int kh_ = tap_ / 3, kw_ = tap_ - kh_ * 3;                                  \
    const signed char* s_ = xbp + (kh_ * WP + kw_) * CIN + ((ktx) & 3) * 64;   \
    gload_lds16(s_,      dstB + (BO));                                         \
    gload_lds16(s_ + 16, dstB + (BO) + 4096);                                  \
    gload_lds16(s_ + 32, dstB + (BO) + 8192);                                  \
    gload_lds16(s_ + 48, dstB + (BO) + 12288);                                 \
  } while (0)

    // prologue: kt0 -> buf0, kt1 -> buf1 (12 loads); wait kt0 (keep 6)
    STAGE_Ak(0, 0); STAGE_Bk(0, 0);
    STAGE_Ak(1, 24576); STAGE_Bk(1, 24576);
    asm volatile("s_waitcnt vmcnt(6)" ::: "memory");
    __builtin_amdgcn_sched_barrier(0);
    __builtin_amdgcn_s_barrier();
    __builtin_amdgcn_sched_barrier(0);

    int rb = 0, sb = 49152;   // read / stage byte offsets (tri-buffer)
    i32x4 af[4], bf[4];

#pragma unroll 1
    for (int kt = 0; kt < NT; ++kt) {
      const int kn = (kt + 2 < NT) ? kt + 2 : NT - 1;   // tail dummy ok
      // P1: A-frags + B-frags nf0..3; stage A(kt+2); MFMA quadrant
      if (run) {
        #pragma unroll
        for (int i_ = 0; i_ < 4; ++i_)
          af[i_] = *(const i32x4*)(smem + rb + abase0 + i_ * 256);
        #pragma unroll
        for (int j_ = 0; j_ < 4; ++j_)
          bf[j_] = *(const i32x4*)(smem + rb + bbase0 + j_ * 256);
      }
      STAGE_Ak(kn, sb);
      if (run) {
        __builtin_amdgcn_s_setprio(1);
        #pragma unroll
        for (int m_ = 0; m_ < 4; ++m_)
          #pragma unroll
          for (int n_ = 0; n_ < 4; ++n_)
            acc[m_][n_] = __builtin_amdgcn_mfma_i32_16x16x64_i8(
                af[m_], bf[n_], acc[m_][n_], 0, 0, 0);
        __builtin_amdgcn_s_setprio(0);
      }
      __builtin_amdgcn_s_barrier();
      __builtin_amdgcn_sched_barrier(0);
      // P2: B-frags nf4..7; stage B(kt+2); MFMA quadrant; counted drain
      if (run) {
        #pragma unroll
        for (int j_ = 0; j_ < 4; ++j_)
          bf[j_] = *(const i32x4*)(smem + rb + bbase0 + 1024 + j_ * 256);
      }
      STAGE_Bk(kn, sb);
      if (run) {
        __builtin_amdgcn_s_setprio(1);
        #pragma unroll
        for (int m_ = 0; m_ < 4; ++m_)
          #pragma unroll
          for (int n_ = 0; n_ < 4; ++n_)
            acc[m_][n_ + 4] = __builtin_amdgcn_mfma_i32_16x16x64_i8(
                af[m_], bf[n_], acc[m_][n_ + 4], 0, 0, 0);
        __builtin_amdgcn_s_setprio(0);
      }
      asm volatile("s_waitcnt vmcnt(6)" ::: "memory");
      __builtin_amdgcn_sched_barrier(0);
      __builtin_amdgcn_s_barrier();
      __builtin_amdgcn_sched_barrier(0);
      // rotate tri-buffer: freed read buffer becomes next stage target
      int nrb = (rb == 49152) ? 0 : rb + 24576;
      sb = rb;
      rb = nrb;
    }
    asm volatile("s_waitcnt vmcnt(0)" ::: "memory");  // drain tail dummies
  }

  // epilogue: C/D map col(n)=lane&15, row(m)=(lane>>4)*4+reg.
  // slot -> co via perm; skipped/padded rows carry exact zeros.
  const int* perm = meta + 1;
  #pragma unroll
  for (int m = 0; m < 4; ++m) {
    const int slotb = by * 128 + wm * 64 + m * 16 + lr * 4;
    const int c0 = perm[slotb], c1 = perm[slotb + 1];
    const int c2 = perm[slotb + 2], c3 = perm[slotb + 3];
    const int cos[4] = {c0, c1, c2, c3};
    #pragma unroll
    for (int nf = 0; nf < 8; ++nf) {
      const int col = wn * 128 + nf * 16 + lc;
      const int h = h0 + (col >> 6);
      const int w = col & 63;
      if (w < Ww) {
        #pragma unroll
        for (int r = 0; r < 4; ++r)
          out[(((size_t)b * COUT + cos[r]) * Hh + h) * Ww + w] =
              (float)acc[m][nf][r] * QINV;
      }
    }
  }
}

// ---- fallback: proven-correct naive direct conv (used only if ws too small)
__global__ __launch_bounds__(256) void binconv_naive(
    const float* __restrict__ x,
    const float* __restrict__ wgt,
    const float* __restrict__ mask,
    float* __restrict__ out) {
  const int w  = threadIdx.x;
  const int h  = blockIdx.x * 4 + threadIdx.y;
  const int co = blockIdx.y;
  const int b  = blockIdx.z;

  const float m = mask[co];
  const float scale = (m > 0.f) ? 1.f : ((m < 0.f) ? 0.f : 0.5f);

  const size_t obase = (((size_t)b * COUT + co) * Hh + h) * Ww + w;
  if (scale == 0.f) {
    if (w < Ww) out[obase] = 0.f;
    return;
  }

  const float* __restrict__ xb = x   + (size_t)b  * CIN * Hh * Ww;
  const float* __restrict__ wc = wgt + (size_t)co * CIN * 9;

  float acc = 0.f;
  for (int ci = 0; ci < CIN; ++ci) {
    const float* __restrict__ xc = xb + (size_t)ci * (Hh * Ww);
    const float* __restrict__ wk = wc + ci * 9;
    float wv[9];
    #pragma unroll
    for (int t2 = 0; t2 < 9; ++t2) wv[t2] = wk[t2];
    #pragma unroll
    for (int kh = 0; kh < 3; ++kh) {
      const int hh = h + kh - 1;
      if (hh < 0 || hh >= Hh) continue;
      const float* __restrict__ xr = xc + hh * Ww;
      #pragma unroll
      for (int kw = 0; kw < 3; ++kw) {
        const int ww = w + kw - 1;
        float xv = (ww >= 0 && ww < Ww) ? xr[ww] : 0.f;
        float s = (xv > 0.f) ? 1.f : ((xv < 0.f) ? -1.f : 0.f);
        acc += s * wv[kh * 3 + kw];
      }
    }
  }
  if (w < Ww) out[obase] = acc * scale;
}

extern "C" void kernel_launch(void* const* d_in, const int* in_sizes, int n_in,
                              void* d_out, int out_size, void* d_ws, size_t ws_size,
                              hipStream_t stream) {
  const float* x    = (const float*)d_in[0];
  const float* wgt  = (const float*)d_in[1];
  const float* mask = (const float*)d_in[2];
  float* out = (float*)d_out;

  bool ok = ws_size >= WS_REQUIRED;
  if (ok) {
    hipError_t e = hipFuncSetAttribute(
        (const void*)gemm_i8c, hipFuncAttributeMaxDynamicSharedMemorySize,
        73728);
    ok = (e == hipSuccess);
  }
  if (!ok) {
    hipLaunchKernelGGL(binconv_naive, dim3(Hh / 4, COUT, B_), dim3(64, 4, 1),
                       0, stream, x, wgt, mask, out);
    return;
  }

  signed char* xp8 = (signed char*)d_ws;
  signed char* awt = (signed char*)d_ws + AWT_OFF;
  int* meta        = (int*)((char*)d_ws + META_OFF);

  hipLaunchKernelGGL(perm_k, dim3(1), dim3(256), 0, stream, mask, meta);
  hipLaunchKernelGGL(prep_w8, dim3(COUT), dim3(256), 0, stream, wgt, mask,
                     meta, awt);
  hipLaunchKernelGGL(prep_x8, dim3(HP, B_), dim3(256), 0, stream, x, xp8);
  hipLaunchKernelGGL(gemm_i8c, dim3(448, 2), dim3(256), 73728, stream,
                     xp8, awt, meta, out);
}

// Round 16
// 122.785 us; speedup vs baseline: 1.4345x; 1.0182x over previous
//
#include <hip/hip_runtime.h>

#define B_    32
#define CIN   256
#define COUT  256
#define Hh    56
#define Ww    56
#define HP    58
#define WP    58
#define Kk    2304   // 9 taps * 256 ci
#define NT    36     // K-tiles of BK=64

#define QSCALE 2016.0f
#define QINV   (1.0f/2016.0f)

#define XPAD_BYTES ((size_t)B_*HP*WP*CIN)     // 27,557,888 i8
#define XPAD_GUARD 4096                        // wp-overrun guard (reads only)
#define AWT_OFF    (XPAD_BYTES + XPAD_GUARD)
#define AWT_BYTES  ((size_t)NT*16384)          // weights tiled [kt][kc][slot][16]
#define META_OFF   (AWT_OFF + AWT_BYTES)
#define WS_REQUIRED (META_OFF + 1040)

typedef __attribute__((ext_vector_type(4))) int i32x4;

__device__ __forceinline__ void gload_lds16(const void* g, void* l) {
  __builtin_amdgcn_global_load_lds(
      (const __attribute__((address_space(1))) unsigned int*)g,
      (__attribute__((address_space(3))) unsigned int*)l, 16, 0, 0);
}

// ---- prepass 1: gated weights -> i8, compacted-slot tiled [kt][kc][slot][16]
// Each block recomputes the mask scan locally (perm); block 0 writes meta
// (meta[0]=act, meta[1..256]=perm) for the gemm epilogue.
__global__ __launch_bounds__(256) void prep_w8(const float* __restrict__ wgt,
                                               const float* __restrict__ mask,
                                               int* __restrict__ meta,
                                               signed char* __restrict__ awt) {
  __shared__ int sc[256];
  __shared__ int sperm[256];
  const int t = threadIdx.x;
  const int fl = (mask[t] >= 0.0f) ? 1 : 0;   // scale!=0 iff mask>=0
  sc[t] = fl;
  __syncthreads();
  for (int off = 1; off < 256; off <<= 1) {
    int v = sc[t];
    int u = (t >= off) ? sc[t - off] : 0;
    __syncthreads();
    sc[t] = v + u;
    __syncthreads();
  }
  const int incl = sc[t], act = sc[255];
  const int pos = fl ? (incl - 1) : (act + t - incl);
  sperm[pos] = t;
  __syncthreads();
  if (blockIdx.x == 0) {
    meta[1 + pos] = t;
    if (t == 0) meta[0] = act;
  }
  const int slot = blockIdx.x;
  const int co = sperm[slot];
  const float m = mask[co];
  const float scl = (m > 0.f ? 1.f : (m < 0.f ? 0.f : 0.5f)) * QSCALE;
  const float* wc = wgt + (size_t)co * Kk;       // [ci][tap]
  for (int o = t; o < Kk; o += 256) {
    int tap = o >> 8, ci = o & 255;
    int q = __float2int_rn(wc[ci * 9 + tap] * scl);
    int kt = tap * 4 + (ci >> 6);
    int kk = ci & 63;
    awt[((size_t)kt * 1024 + (kk >> 4) * 256 + slot) * 16 + (kk & 15)] =
        (signed char)q;
  }
}

// ---- prepass 2: sign(x) -> i8 {-1,0,1}, zero-pad, NCHW -> [b][hp][wp][ci]
__global__ __launch_bounds__(256) void prep_x8(const float* __restrict__ x,
                                               signed char* __restrict__ xp) {
  const int hp = blockIdx.x, b = blockIdx.y, t = threadIdx.x;
  unsigned* orow = (unsigned*)(xp + (size_t)(b * HP + hp) * WP * CIN);
  if (hp == 0 || hp == HP - 1) {
    for (int i = t; i < WP * CIN / 4; i += 256) orow[i] = 0u;
    return;
  }
  __shared__ __align__(16) signed char tile[WP * CIN];
  const int h = hp - 1;
  tile[t] = 0;
  tile[(WP - 1) * CIN + t] = 0;
  const int tx = t & 63, ty = t >> 6;
  if (tx < Ww) {
    const float* xr = x + ((size_t)b * CIN * Hh + h) * Ww;
    for (int ci = ty; ci < CIN; ci += 4) {
      float xv = xr[(size_t)ci * Hh * Ww + tx];
      tile[(1 + tx) * CIN + ci] = (xv > 0.f) ? 1 : (xv < 0.f ? -1 : 0);
    }
  }
  __syncthreads();
  for (int i = t; i < WP * CIN / 4; i += 256) orow[i] = ((const unsigned*)tile)[i];
}

// ---- main: compacted-M i8 GEMM with software-pipelined fragment reads.
// Geometry = r14: BM=128 (grid_y=2), BN=256, BK=64, 4 waves of 64Mx128N,
// tri-buffer LDS (3 x 24KB: A 8KB + B 16KB), depth-2 DMA prefetch.
// Per KT: P1 {read bf_h1(kt) | STAGE_A(kt+2) | MFMA h0 | vmcnt(2) | bar}
//         P2 {read af/bf_h0(kt+1) from published buf | STAGE_B(kt+2) |
//             MFMA h1 | bar}. All ds_read waits land under 16 MFMAs.
// grid=(448 = b*14 + hblk, 2), block=256
__global__ __launch_bounds__(256, 2) void gemm_i8p(
    const signed char* __restrict__ xp,
    const signed char* __restrict__ awt,
    const int* __restrict__ meta,
    float* __restrict__ out) {
  extern __shared__ char smem[];

  const int t = threadIdx.x;
  const int nb = blockIdx.x, by = blockIdx.y;
  const int b = nb / 14, h0 = (nb % 14) * 4;

  const int act = meta[0];
  const int rem = act - by * 128;
  const int ng = (rem <= 0) ? 0 : ((rem > 64) ? 2 : 1);

  const int wid = t >> 6, lane = t & 63;
  const int wm = wid >> 1, wn = wid & 1;     // wave tile: 64 M x 128 N
  const int lc = lane & 15, lr = lane >> 4;

  i32x4 acc[4][8] = {};

  if (ng > 0) {
    const signed char* awp =
        awt + (t >> 7) * 4096 + (size_t)(by * 128 + (t & 127)) * 16;
    const size_t xb = (size_t)b * HP;
    const signed char* xbp =
        xp + ((xb + h0 + (t >> 6)) * WP + (t & 63)) * CIN;
    char* dstA = smem + t * 16;
    char* dstB = smem + 8192 + t * 16;

    const int abase0 = lr * 2048 + (wm * 64 + lc) * 16;
    const int bbase0 = 8192 + lr * 4096 + (wn * 128 + lc) * 16;
    const bool run = (wm < ng);

#define STAGE_Ak(ktx, BO) do {                                                 \
    const signed char* s_ = awp + (size_t)(ktx) * 16384;                       \
    gload_lds16(s_, dstA + (BO));                                              \
    gload_lds16(s_ + 8192, dstA + (BO) + 4096);                                \
  } while (0)

#define STAGE_Bk(ktx, BO) do {                                                 \
    int tap_ = (ktx) >> 2;                                                     \
    int kh_ = tap_ / 3, kw_ = tap_ - kh_ * 3;                                  \
    const signed char* s_ = xbp + (kh_ * WP + kw_) * CIN + ((ktx) & 3) * 64;   \
    gload_lds16(s_,      dstB + (BO));                                         \
    gload_lds16(s_ + 16, dstB + (BO) + 4096);                                  \
    gload_lds16(s_ + 32, dstB + (BO) + 8192);                                  \
    gload_lds16(s_ + 48, dstB + (BO) + 12288);                                 \
  } while (0)

    // prologue: kt0 -> buf0, kt1 -> buf1 (12 loads); drain kt0 (keep 6)
    STAGE_Ak(0, 0); STAGE_Bk(0, 0);
    STAGE_Ak(1, 24576); STAGE_Bk(1, 24576);
    asm volatile("s_waitcnt vmcnt(6)" ::: "memory");
    __builtin_amdgcn_sched_barrier(0);
    __builtin_amdgcn_s_barrier();
    __builtin_amdgcn_sched_barrier(0);

    int rb = 0, rbn = 24576, sb = 49152;
    i32x4 afA[4], bhA[4], afB[4], bhB[4], bf1[4];

    // preload kt0 fragments (af + b-half0) from buf0
    if (run) {
      #pragma unroll
      for (int i_ = 0; i_ < 4; ++i_) {
        afA[i_] = *(const i32x4*)(smem + rb + abase0 + i_ * 256);
        bhA[i_] = *(const i32x4*)(smem + rb + bbase0 + i_ * 256);
      }
    }

#define KT_STEP(kt, AFC, BHC, AFN, BHN) do {                                   \
    const int kn_ = ((kt) + 2 < NT) ? (kt) + 2 : NT - 1;                       \
    /* P1: read b-half1(kt); stage A(kt+2); MFMA h0 */                         \
    if (run) { _Pragma("unroll")                                               \
      for (int j_ = 0; j_ < 4; ++j_)                                           \
        bf1[j_] = *(const i32x4*)(smem + rb + bbase0 + 1024 + j_ * 256);       \
    }                                                                          \
    STAGE_Ak(kn_, sb);                                                         \
    if (run) {                                                                 \
      __builtin_amdgcn_s_setprio(1);                                           \
      _Pragma("unroll")                                                        \
      for (int m_ = 0; m_ < 4; ++m_) { _Pragma("unroll")                       \
        for (int n_ = 0; n_ < 4; ++n_)                                         \
          acc[m_][n_] = __builtin_amdgcn_mfma_i32_16x16x64_i8(                 \
              AFC[m_], BHC[n_], acc[m_][n_], 0, 0, 0); }                       \
      __builtin_amdgcn_s_setprio(0);                                           \
    }                                                                          \
    asm volatile("s_waitcnt vmcnt(2)" ::: "memory");                           \
    __builtin_amdgcn_sched_barrier(0);                                         \
    __builtin_amdgcn_s_barrier();                                              \
    __builtin_amdgcn_sched_barrier(0);                                         \
    /* P2: prefetch af/b-half0 of kt+1 (buffer just published); stage B;   */  \
    /*     MFMA h1 */                                                          \
    if (run) { _Pragma("unroll")                                               \
      for (int i_ = 0; i_ < 4; ++i_) {                                         \
        AFN[i_] = *(const i32x4*)(smem + rbn + abase0 + i_ * 256);             \
        BHN[i_] = *(const i32x4*)(smem + rbn + bbase0 + i_ * 256);             \
      }                                                                        \
    }                                                                          \
    STAGE_Bk(kn_, sb);                                                         \
    if (run) {                                                                 \
      __builtin_amdgcn_s_setprio(1);                                           \
      _Pragma("unroll")                                                        \
      for (int m_ = 0; m_ < 4; ++m_) { _Pragma("unroll")                       \
        for (int n_ = 0; n_ < 4; ++n_)                                         \
          acc[m_][n_ + 4] = __builtin_amdgcn_mfma_i32_16x16x64_i8(             \
              AFC[m_], bf1[n_], acc[m_][n_ + 4], 0, 0, 0); }                   \
      __builtin_amdgcn_s_setprio(0);                                           \
    }                                                                          \
    __builtin_amdgcn_s_barrier();                                              \
    __builtin_amdgcn_sched_barrier(0);                                         \
    { int tmp_ = rb; rb = rbn; rbn = sb; sb = tmp_; }                          \
  } while (0)

#pragma unroll 1
    for (int it = 0; it < NT / 2; ++it) {
      KT_STEP(2 * it,     afA, bhA, afB, bhB);
      KT_STEP(2 * it + 1, afB, bhB, afA, bhA);
    }
    asm volatile("s_waitcnt vmcnt(0)" ::: "memory");  // drain tail dummies
  }

  // epilogue: C/D map col(n)=lane&15, row(m)=(lane>>4)*4+reg.
  // slot -> co via perm; skipped/padded rows carry exact zeros.
  const int* perm = meta + 1;
  #pragma unroll
  for (int m = 0; m < 4; ++m) {
    const int slotb = by * 128 + wm * 64 + m * 16 + lr * 4;
    const int c0 = perm[slotb], c1 = perm[slotb + 1];
    const int c2 = perm[slotb + 2], c3 = perm[slotb + 3];
    const int cos[4] = {c0, c1, c2, c3};
    #pragma unroll
    for (int nf = 0; nf < 8; ++nf) {
      const int col = wn * 128 + nf * 16 + lc;
      const int h = h0 + (col >> 6);
      const int w = col & 63;
      if (w < Ww) {
        #pragma unroll
        for (int r = 0; r < 4; ++r)
          out[(((size_t)b * COUT + cos[r]) * Hh + h) * Ww + w] =
              (float)acc[m][nf][r] * QINV;
      }
    }
  }
}

// ---- fallback: proven-correct naive direct conv (used only if ws too small)
__global__ __launch_bounds__(256) void binconv_naive(
    const float* __restrict__ x,
    const float* __restrict__ wgt,
    const float* __restrict__ mask,
    float* __restrict__ out) {
  const int w  = threadIdx.x;
  const int h  = blockIdx.x * 4 + threadIdx.y;
  const int co = blockIdx.y;
  const int b  = blockIdx.z;

  const float m = mask[co];
  const float scale = (m > 0.f) ? 1.f : ((m < 0.f) ? 0.f : 0.5f);

  const size_t obase = (((size_t)b * COUT + co) * Hh + h) * Ww + w;
  if (scale == 0.f) {
    if (w < Ww) out[obase] = 0.f;
    return;
  }

  const float* __restrict__ xb = x   + (size_t)b  * CIN * Hh * Ww;
  const float* __restrict__ wc = wgt + (size_t)co * CIN * 9;

  float acc = 0.f;
  for (int ci = 0; ci < CIN; ++ci) {
    const float* __restrict__ xc = xb + (size_t)ci * (Hh * Ww);
    const float* __restrict__ wk = wc + ci * 9;
    float wv[9];
    #pragma unroll
    for (int t2 = 0; t2 < 9; ++t2) wv[t2] = wk[t2];
    #pragma unroll
    for (int kh = 0; kh < 3; ++kh) {
      const int hh = h + kh - 1;
      if (hh < 0 || hh >= Hh) continue;
      const float* __restrict__ xr = xc + hh * Ww;
      #pragma unroll
      for (int kw = 0; kw < 3; ++kw) {
        const int ww = w + kw - 1;
        float xv = (ww >= 0 && ww < Ww) ? xr[ww] : 0.f;
        float s = (xv > 0.f) ? 1.f : ((xv < 0.f) ? -1.f : 0.f);
        acc += s * wv[kh * 3 + kw];
      }
    }
  }
  if (w < Ww) out[obase] = acc * scale;
}

extern "C" void kernel_launch(void* const* d_in, const int* in_sizes, int n_in,
                              void* d_out, int out_size, void* d_ws, size_t ws_size,
                              hipStream_t stream) {
  const float* x    = (const float*)d_in[0];
  const float* wgt  = (const float*)d_in[1];
  const float* mask = (const float*)d_in[2];
  float* out = (float*)d_out;

  bool ok = ws_size >= WS_REQUIRED;
  if (ok) {
    hipError_t e = hipFuncSetAttribute(
        (const void*)gemm_i8p, hipFuncAttributeMaxDynamicSharedMemorySize,
        73728);
    ok = (e == hipSuccess);
  }
  if (!ok) {
    hipLaunchKernelGGL(binconv_naive, dim3(Hh / 4, COUT, B_), dim3(64, 4, 1),
                       0, stream, x, wgt, mask, out);
    return;
  }

  signed char* xp8 = (signed char*)d_ws;
  signed char* awt = (signed char*)d_ws + AWT_OFF;
  int* meta        = (int*)((char*)d_ws + META_OFF);

  hipLaunchKernelGGL(prep_w8, dim3(COUT), dim3(256), 0, stream, wgt, mask,
                     meta, awt);
  hipLaunchKernelGGL(prep_x8, dim3(HP, B_), dim3(256), 0, stream, x, xp8);
  hipLaunchKernelGGL(gemm_i8p, dim3(448, 2), dim3(256), 73728, stream,
                     xp8, awt, meta, out);
}